// Round 1
// baseline (555.991 us; speedup 1.0000x reference)
//
#include <hip/hip_runtime.h>
#include <hip/hip_bf16.h>

#define NBATCH 4
#define NS 2048
#define NE 1024
#define NH 16
#define ND 64

typedef __attribute__((ext_vector_type(4))) float f32x4;
typedef __attribute__((ext_vector_type(8))) short s16x8;

__device__ __forceinline__ unsigned short f2bf(float f) {
  union { float f; unsigned u; } v; v.f = f;
  return (unsigned short)((v.u + 0x7fffu + ((v.u >> 16) & 1u)) >> 16);
}

// ---------------- convert f32 -> bf16 for x, W_qkv, W_out ----------------
__global__ __launch_bounds__(256) void cvt_kernel(
    const float* __restrict__ x, const float* __restrict__ wqkv,
    const float* __restrict__ wout, unsigned short* __restrict__ xb,
    unsigned short* __restrict__ wqb, unsigned short* __restrict__ wob) {
  const int NX = NBATCH * NS * NE / 4, NQ = NH * 3 * ND * ND / 4, NO = NE * NE / 4;
  const int total = NX + NQ + NO;
  for (int i = blockIdx.x * blockDim.x + threadIdx.x; i < total;
       i += gridDim.x * blockDim.x) {
    const float4* s; unsigned short* d; int j;
    if (i < NX)           { s = (const float4*)x;    d = xb;  j = i; }
    else if (i < NX + NQ) { s = (const float4*)wqkv; d = wqb; j = i - NX; }
    else                  { s = (const float4*)wout; d = wob; j = i - NX - NQ; }
    float4 v = s[j];
    ushort4 o;
    o.x = f2bf(v.x); o.y = f2bf(v.y); o.z = f2bf(v.z); o.w = f2bf(v.w);
    ((ushort4*)d)[j] = o;
  }
}

// ---------------- per-head QKV projection (MFMA) ----------------
// out layouts: Qb,Kb [B*H, S, D] bf16 (Q pre-scaled by 1/8); Vt [B*H, D, S] bf16
__global__ __launch_bounds__(256) void qkv_kernel(
    const unsigned short* __restrict__ xb, const unsigned short* __restrict__ wqb,
    unsigned short* __restrict__ Qb, unsigned short* __restrict__ Kb,
    unsigned short* __restrict__ Vt) {
  int blk = blockIdx.x;
  int st = blk & 31;        // S/64 = 32 s-tiles
  int bh = blk >> 5;        // 0..63
  int h = bh & 15;
  int b = bh >> 4;
  int tid = threadIdx.x, w = tid >> 6, l = tid & 63, lm = l & 15, lg = l >> 4;
  int s0 = st * 64 + w * 16;

  const unsigned short* xrow = xb + (size_t)(b * NS + s0 + lm) * NE + h * ND;
  s16x8 a0 = *(const s16x8*)(xrow + lg * 8);
  s16x8 a1 = *(const s16x8*)(xrow + 32 + lg * 8);
  const unsigned short* wb = wqb + h * 3 * ND * ND;
  size_t bhS = (size_t)bh * NS;

#pragma unroll
  for (int nb = 0; nb < 12; nb++) {
    f32x4 acc = (f32x4){0.f, 0.f, 0.f, 0.f};
    const unsigned short* wr_ = wb + (nb * 16 + lm) * ND + lg * 8;
    acc = __builtin_amdgcn_mfma_f32_16x16x32_bf16(a0, *(const s16x8*)wr_, acc, 0, 0, 0);
    acc = __builtin_amdgcn_mfma_f32_16x16x32_bf16(a1, *(const s16x8*)(wr_ + 32), acc, 0, 0, 0);
    int e = nb * 16 + lm;
    if (nb < 4) {
#pragma unroll
      for (int r = 0; r < 4; r++)
        Qb[(bhS + s0 + lg * 4 + r) * ND + e] = f2bf(acc[r] * 0.125f);
    } else if (nb < 8) {
#pragma unroll
      for (int r = 0; r < 4; r++)
        Kb[(bhS + s0 + lg * 4 + r) * ND + (e - 64)] = f2bf(acc[r]);
    } else {
#pragma unroll
      for (int r = 0; r < 4; r++)
        Vt[((size_t)bh * ND + (e - 128)) * NS + s0 + lg * 4 + r] = f2bf(acc[r]);
    }
  }
}

// ---------------- flash attention ----------------
// Q pre-scaled. 4 waves/block, each wave owns 16 q rows; KV tile = 64.
__global__ __launch_bounds__(256) void attn_kernel(
    const unsigned short* __restrict__ Qb, const unsigned short* __restrict__ Kb,
    const unsigned short* __restrict__ Vt, unsigned short* __restrict__ AOb) {
  __shared__ __align__(16) unsigned short plds[4][16][72];
  int blk = blockIdx.x;
  int qt = blk & 31;        // S/64
  int bh = blk >> 5;
  int h = bh & 15;
  int b = bh >> 4;
  int tid = threadIdx.x, w = tid >> 6, l = tid & 63, lm = l & 15, lg = l >> 4;
  int q0 = qt * 64 + w * 16;

  const unsigned short* Qh = Qb + (size_t)bh * NS * ND;
  const unsigned short* Kh = Kb + (size_t)bh * NS * ND;
  const unsigned short* Vh = Vt + (size_t)bh * ND * NS;

  s16x8 qf0 = *(const s16x8*)(Qh + (size_t)(q0 + lm) * ND + lg * 8);
  s16x8 qf1 = *(const s16x8*)(Qh + (size_t)(q0 + lm) * ND + 32 + lg * 8);

  f32x4 acco[4];
#pragma unroll
  for (int i = 0; i < 4; i++) acco[i] = (f32x4){0.f, 0.f, 0.f, 0.f};
  float mreg[4], lsum[4];
#pragma unroll
  for (int r = 0; r < 4; r++) { mreg[r] = -1e30f; lsum[r] = 0.f; }

  for (int kv0 = 0; kv0 < NS; kv0 += 64) {
    // S = Q K^T  (16 x 64)
    f32x4 accs[4];
#pragma unroll
    for (int nb = 0; nb < 4; nb++) {
      accs[nb] = (f32x4){0.f, 0.f, 0.f, 0.f};
      const unsigned short* kp = Kh + (size_t)(kv0 + nb * 16 + lm) * ND + lg * 8;
      accs[nb] = __builtin_amdgcn_mfma_f32_16x16x32_bf16(qf0, *(const s16x8*)kp, accs[nb], 0, 0, 0);
      accs[nb] = __builtin_amdgcn_mfma_f32_16x16x32_bf16(qf1, *(const s16x8*)(kp + 32), accs[nb], 0, 0, 0);
    }
    // online softmax (rows = lg*4 + r)
#pragma unroll
    for (int r = 0; r < 4; r++) {
      float v = fmaxf(fmaxf(accs[0][r], accs[1][r]), fmaxf(accs[2][r], accs[3][r]));
#pragma unroll
      for (int msk = 1; msk < 16; msk <<= 1) v = fmaxf(v, __shfl_xor(v, msk));
      float mn = fmaxf(mreg[r], v);
      float sc = __expf(mreg[r] - mn);
      mreg[r] = mn;
      float pr[4];
      float ps = 0.f;
#pragma unroll
      for (int nb = 0; nb < 4; nb++) { pr[nb] = __expf(accs[nb][r] - mn); ps += pr[nb]; }
#pragma unroll
      for (int msk = 1; msk < 16; msk <<= 1) ps += __shfl_xor(ps, msk);
      lsum[r] = lsum[r] * sc + ps;
#pragma unroll
      for (int nb = 0; nb < 4; nb++) {
        acco[nb][r] *= sc;
        plds[w][lg * 4 + r][nb * 16 + lm] = f2bf(pr[nb]);
      }
    }
    // wave-internal LDS transpose fence (cross-lane dependency)
    asm volatile("s_waitcnt lgkmcnt(0)" ::: "memory");
    // O += P V
#pragma unroll
    for (int kc = 0; kc < 2; kc++) {
      s16x8 pa = *(const s16x8*)&plds[w][lm][kc * 32 + lg * 8];
#pragma unroll
      for (int nb = 0; nb < 4; nb++) {
        const unsigned short* vp = Vh + (size_t)(nb * 16 + lm) * NS + kv0 + kc * 32 + lg * 8;
        acco[nb] = __builtin_amdgcn_mfma_f32_16x16x32_bf16(pa, *(const s16x8*)vp, acco[nb], 0, 0, 0);
      }
    }
  }
  // normalize + write [B, S, E] bf16
#pragma unroll
  for (int nb = 0; nb < 4; nb++) {
#pragma unroll
    for (int r = 0; r < 4; r++) {
      float v = acco[nb][r] / lsum[r];
      AOb[((size_t)b * NS + q0 + lg * 4 + r) * NE + h * ND + nb * 16 + lm] = f2bf(v);
    }
  }
}

// ---------------- output projection GEMM: C[M,N] = A[M,K] * B[N,K]^T ----------------
// M = B*S = 8192, N = K = 1024. 128x128 block tile, 4 waves of 64x64.
__global__ __launch_bounds__(256) void proj_kernel(
    const unsigned short* __restrict__ A, const unsigned short* __restrict__ Bw,
    float* __restrict__ C) {
  int blk = blockIdx.x;
  int bn = blk & 7;     // N/128 = 8
  int bm = blk >> 3;
  int tid = threadIdx.x, w = tid >> 6, l = tid & 63, lm = l & 15, lg = l >> 4;
  int m0 = bm * 128 + (w >> 1) * 64;
  int n0 = bn * 128 + (w & 1) * 64;

  f32x4 acc[4][4];
#pragma unroll
  for (int i = 0; i < 4; i++)
#pragma unroll
    for (int j = 0; j < 4; j++) acc[i][j] = (f32x4){0.f, 0.f, 0.f, 0.f};

  for (int k = 0; k < NE; k += 32) {
    s16x8 af[4], bf[4];
#pragma unroll
    for (int mb = 0; mb < 4; mb++)
      af[mb] = *(const s16x8*)(A + (size_t)(m0 + mb * 16 + lm) * NE + k + lg * 8);
#pragma unroll
    for (int nb = 0; nb < 4; nb++)
      bf[nb] = *(const s16x8*)(Bw + (size_t)(n0 + nb * 16 + lm) * NE + k + lg * 8);
#pragma unroll
    for (int mb = 0; mb < 4; mb++)
#pragma unroll
      for (int nb = 0; nb < 4; nb++)
        acc[mb][nb] = __builtin_amdgcn_mfma_f32_16x16x32_bf16(af[mb], bf[nb], acc[mb][nb], 0, 0, 0);
  }
#pragma unroll
  for (int mb = 0; mb < 4; mb++)
#pragma unroll
    for (int nb = 0; nb < 4; nb++)
#pragma unroll
      for (int r = 0; r < 4; r++)
        C[(size_t)(m0 + mb * 16 + lg * 4 + r) * NE + n0 + nb * 16 + lm] = acc[mb][nb][r];
}

extern "C" void kernel_launch(void* const* d_in, const int* in_sizes, int n_in,
                              void* d_out, int out_size, void* d_ws, size_t ws_size,
                              hipStream_t stream) {
  const float* x    = (const float*)d_in[0];
  const float* wqkv = (const float*)d_in[1];
  const float* wout = (const float*)d_in[2];
  float* out = (float*)d_out;
  char* ws = (char*)d_ws;

  size_t off = 0;
  unsigned short* xb  = (unsigned short*)(ws + off); off += (size_t)NBATCH * NS * NE * 2;
  unsigned short* wqb = (unsigned short*)(ws + off); off += (size_t)NH * 3 * ND * ND * 2;
  unsigned short* wob = (unsigned short*)(ws + off); off += (size_t)NE * NE * 2;
  unsigned short* Qb  = (unsigned short*)(ws + off); off += (size_t)NBATCH * NH * NS * ND * 2;
  unsigned short* Kb  = (unsigned short*)(ws + off); off += (size_t)NBATCH * NH * NS * ND * 2;
  unsigned short* Vt  = (unsigned short*)(ws + off); off += (size_t)NBATCH * NH * NS * ND * 2;
  unsigned short* AOb = (unsigned short*)(ws + off); off += (size_t)NBATCH * NS * NE * 2;

  cvt_kernel<<<2048, 256, 0, stream>>>(x, wqkv, wout, xb, wqb, wob);
  qkv_kernel<<<2048, 256, 0, stream>>>(xb, wqb, Qb, Kb, Vt);
  attn_kernel<<<2048, 256, 0, stream>>>(Qb, Kb, Vt, AOb);
  proj_kernel<<<512, 256, 0, stream>>>(AOb, wob, out);
}

// Round 2
// 345.323 us; speedup vs baseline: 1.6101x; 1.6101x over previous
//
#include <hip/hip_runtime.h>
#include <hip/hip_bf16.h>

#define NBATCH 4
#define NS 2048
#define NE 1024
#define NH 16
#define ND 64

typedef __attribute__((ext_vector_type(4))) float f32x4;
typedef __attribute__((ext_vector_type(16))) float f32x16;
typedef __attribute__((ext_vector_type(8))) short s16x8;

__device__ __forceinline__ unsigned short f2bf(float f) {
  union { float f; unsigned u; } v; v.f = f;
  return (unsigned short)((v.u + 0x7fffu + ((v.u >> 16) & 1u)) >> 16);
}

__device__ __forceinline__ unsigned cvt_pk_bf16(float lo, float hi) {
  unsigned r;
  asm("v_cvt_pk_bf16_f32 %0, %1, %2" : "=v"(r) : "v"(lo), "v"(hi));
  return r;
}

// ---------------- convert f32 -> bf16 for x, W_qkv, W_out ----------------
__global__ __launch_bounds__(256) void cvt_kernel(
    const float* __restrict__ x, const float* __restrict__ wqkv,
    const float* __restrict__ wout, unsigned short* __restrict__ xb,
    unsigned short* __restrict__ wqb, unsigned short* __restrict__ wob) {
  const int NX = NBATCH * NS * NE / 4, NQ = NH * 3 * ND * ND / 4, NO = NE * NE / 4;
  const int total = NX + NQ + NO;
  for (int i = blockIdx.x * blockDim.x + threadIdx.x; i < total;
       i += gridDim.x * blockDim.x) {
    const float4* s; unsigned short* d; int j;
    if (i < NX)           { s = (const float4*)x;    d = xb;  j = i; }
    else if (i < NX + NQ) { s = (const float4*)wqkv; d = wqb; j = i - NX; }
    else                  { s = (const float4*)wout; d = wob; j = i - NX - NQ; }
    float4 v = s[j];
    ushort4 o;
    o.x = f2bf(v.x); o.y = f2bf(v.y); o.z = f2bf(v.z); o.w = f2bf(v.w);
    ((ushort4*)d)[j] = o;
  }
}

// ---------------- per-head QKV projection (MFMA) ----------------
// out: Qb,Kb [B*H, S, D] bf16 (Q pre-scaled by log2(e)/sqrt(D)); Vt [B*H, D, S]
__global__ __launch_bounds__(256) void qkv_kernel(
    const unsigned short* __restrict__ xb, const unsigned short* __restrict__ wqb,
    unsigned short* __restrict__ Qb, unsigned short* __restrict__ Kb,
    unsigned short* __restrict__ Vt) {
  int blk = blockIdx.x;
  int st = blk & 31;        // S/64 = 32 s-tiles
  int bh = blk >> 5;        // 0..63
  int h = bh & 15;
  int b = bh >> 4;
  int tid = threadIdx.x, w = tid >> 6, l = tid & 63, lm = l & 15, lg = l >> 4;
  int s0 = st * 64 + w * 16;

  const unsigned short* xrow = xb + (size_t)(b * NS + s0 + lm) * NE + h * ND;
  s16x8 a0 = *(const s16x8*)(xrow + lg * 8);
  s16x8 a1 = *(const s16x8*)(xrow + 32 + lg * 8);
  const unsigned short* wb = wqb + h * 3 * ND * ND;
  size_t bhS = (size_t)bh * NS;
  const float QSCALE = 0.125f * 1.44269504089f;  // 1/sqrt(D) * log2(e)

#pragma unroll
  for (int nb = 0; nb < 12; nb++) {
    f32x4 acc = (f32x4){0.f, 0.f, 0.f, 0.f};
    const unsigned short* wr_ = wb + (nb * 16 + lm) * ND + lg * 8;
    acc = __builtin_amdgcn_mfma_f32_16x16x32_bf16(a0, *(const s16x8*)wr_, acc, 0, 0, 0);
    acc = __builtin_amdgcn_mfma_f32_16x16x32_bf16(a1, *(const s16x8*)(wr_ + 32), acc, 0, 0, 0);
    int e = nb * 16 + lm;
    if (nb < 4) {
#pragma unroll
      for (int r = 0; r < 4; r++)
        Qb[(bhS + s0 + lg * 4 + r) * ND + e] = f2bf(acc[r] * QSCALE);
    } else if (nb < 8) {
#pragma unroll
      for (int r = 0; r < 4; r++)
        Kb[(bhS + s0 + lg * 4 + r) * ND + (e - 64)] = f2bf(acc[r]);
    } else {
#pragma unroll
      for (int r = 0; r < 4; r++)
        Vt[((size_t)bh * ND + (e - 128)) * NS + s0 + lg * 4 + r] = f2bf(acc[r]);
    }
  }
}

// ---------------- flash attention, 32x32 swapped-operand structure ----------------
// 4 waves/block, each wave owns 32 q rows. KVBLK=64 (two 32-row kv tiles).
// S^T = mfma(K, Q): lane (c=lane&31, hi=lane>>5) holds S[q=c][kv rows
// (reg&3)+8*(reg>>2)+4*hi (+32 for tile1)]. Softmax fully in-register.
// PV: O^T = mfma(Vt, P^T). Epilogue transposes via per-wave LDS tile.
__global__ __launch_bounds__(256) void attn_kernel(
    const unsigned short* __restrict__ Qb, const unsigned short* __restrict__ Kb,
    const unsigned short* __restrict__ Vt, unsigned short* __restrict__ AOb) {
  __shared__ __align__(16) unsigned short plds[4][32][68];
  int blk = blockIdx.x;
  // bijective XCD swizzle: nwg=1024, 16 q-blocks per head stay on one XCD
  int wg = (blk & 7) * 128 + (blk >> 3);
  int qt = wg & 15;         // S/128
  int bh = wg >> 4;
  int h = bh & 15;
  int b = bh >> 4;
  int tid = threadIdx.x, w = tid >> 6, l = tid & 63, c = l & 31, hi = l >> 5;
  int q0 = qt * 128 + w * 32;

  const unsigned short* Qh = Qb + (size_t)bh * NS * ND;
  const unsigned short* Kh = Kb + (size_t)bh * NS * ND;
  const unsigned short* Vh = Vt + (size_t)bh * ND * NS;

  // Q B-fragments: col=q=c, k elems = d = dk*16 + hi*8 + j
  s16x8 qf[4];
#pragma unroll
  for (int dk = 0; dk < 4; dk++)
    qf[dk] = *(const s16x8*)(Qh + (size_t)(q0 + c) * ND + dk * 16 + hi * 8);

  f32x16 o0, o1;
#pragma unroll
  for (int r = 0; r < 16; r++) { o0[r] = 0.f; o1[r] = 0.f; }
  float m = -1e30f, lsum = 0.f;

  for (int kv0 = 0; kv0 < NS; kv0 += 64) {
    // S^T = K . Q^T  (two 32x32 tiles over d=64)
    f32x16 s0, s1;
#pragma unroll
    for (int r = 0; r < 16; r++) { s0[r] = 0.f; s1[r] = 0.f; }
    const unsigned short* Kp = Kh + (size_t)(kv0 + c) * ND + hi * 8;
#pragma unroll
    for (int dk = 0; dk < 4; dk++) {
      s16x8 k0 = *(const s16x8*)(Kp + dk * 16);
      s16x8 k1 = *(const s16x8*)(Kp + 32 * ND + dk * 16);
      s0 = __builtin_amdgcn_mfma_f32_32x32x16_bf16(k0, qf[dk], s0, 0, 0, 0);
      s1 = __builtin_amdgcn_mfma_f32_32x32x16_bf16(k1, qf[dk], s1, 0, 0, 0);
    }
    // online softmax in-register (base-2; scale folded into Q)
    float pm = fmaxf(s0[0], s1[0]);
#pragma unroll
    for (int r = 1; r < 16; r++) pm = fmaxf(pm, fmaxf(s0[r], s1[r]));
    pm = fmaxf(pm, __shfl_xor(pm, 32));
    float mn = fmaxf(m, pm);
    float sc = exp2f(m - mn);
    m = mn;
    float ps = 0.f;
#pragma unroll
    for (int r = 0; r < 16; r++) {
      s0[r] = exp2f(s0[r] - mn); ps += s0[r];
      s1[r] = exp2f(s1[r] - mn); ps += s1[r];
    }
    ps += __shfl_xor(ps, 32);
    lsum = lsum * sc + ps;
#pragma unroll
    for (int r = 0; r < 16; r++) { o0[r] *= sc; o1[r] *= sc; }
    // P^T -> bf16 B-fragments in-register (cvt_pk + xor-32 exchange)
    s16x8 pa[4];
#pragma unroll
    for (int ks = 0; ks < 4; ks++) {
      const f32x16& pt = (ks >= 2) ? s1 : s0;
      const int R = (ks & 1) * 8;
      unsigned a0 = cvt_pk_bf16(pt[R + 0], pt[R + 1]);
      unsigned a1 = cvt_pk_bf16(pt[R + 2], pt[R + 3]);
      unsigned b0 = cvt_pk_bf16(pt[R + 4], pt[R + 5]);
      unsigned b1 = cvt_pk_bf16(pt[R + 6], pt[R + 7]);
      unsigned s0_ = hi ? a0 : b0;
      unsigned s1_ = hi ? a1 : b1;
      unsigned r0 = __shfl_xor(s0_, 32);
      unsigned r1 = __shfl_xor(s1_, 32);
      union { unsigned u[4]; s16x8 v; } fr;
      fr.u[0] = hi ? r0 : a0;
      fr.u[1] = hi ? r1 : a1;
      fr.u[2] = hi ? b0 : r0;
      fr.u[3] = hi ? b1 : r1;
      pa[ks] = fr.v;
    }
    // O^T += V^T . P^T  (two d-tiles)
    const unsigned short* Vp = Vh + (size_t)c * NS + kv0 + hi * 8;
#pragma unroll
    for (int ks = 0; ks < 4; ks++) {
      s16x8 v0 = *(const s16x8*)(Vp + ks * 16);
      s16x8 v1 = *(const s16x8*)(Vp + (size_t)32 * NS + ks * 16);
      o0 = __builtin_amdgcn_mfma_f32_32x32x16_bf16(v0, pa[ks], o0, 0, 0, 0);
      o1 = __builtin_amdgcn_mfma_f32_32x32x16_bf16(v1, pa[ks], o1, 0, 0, 0);
    }
  }
  // epilogue: normalize, transpose O^T[d][q] -> [q][d] via LDS, store
  float inv = 1.0f / lsum;
#pragma unroll
  for (int dt = 0; dt < 2; dt++) {
#pragma unroll
    for (int rg = 0; rg < 4; rg++) {
      float v0 = (dt ? o1[rg * 4 + 0] : o0[rg * 4 + 0]) * inv;
      float v1 = (dt ? o1[rg * 4 + 1] : o0[rg * 4 + 1]) * inv;
      float v2 = (dt ? o1[rg * 4 + 2] : o0[rg * 4 + 2]) * inv;
      float v3 = (dt ? o1[rg * 4 + 3] : o0[rg * 4 + 3]) * inv;
      uint2 val;
      val.x = cvt_pk_bf16(v0, v1);
      val.y = cvt_pk_bf16(v2, v3);
      int dbase = dt * 32 + rg * 8 + 4 * hi;  // d of reg rg*4+i is dbase+i
      *reinterpret_cast<uint2*>(&plds[w][c][dbase]) = val;
    }
  }
  asm volatile("s_waitcnt lgkmcnt(0)" ::: "memory");
#pragma unroll
  for (int p = 0; p < 4; p++) {
    int row = p * 8 + (l >> 3);
    int co = (l & 7) * 8;
    uint2 x0 = *reinterpret_cast<const uint2*>(&plds[w][row][co]);
    uint2 x1 = *reinterpret_cast<const uint2*>(&plds[w][row][co + 4]);
    uint4 val; val.x = x0.x; val.y = x0.y; val.z = x1.x; val.w = x1.y;
    *reinterpret_cast<uint4*>(AOb + ((size_t)(b * NS + q0 + row)) * NE + h * ND + co) = val;
  }
}

// ---------------- output projection GEMM: C[M,N] = A[M,K] * B[N,K]^T ----------------
// M = B*S = 8192, N = K = 1024. 128x128 block tile, 4 waves of 64x64.
__global__ __launch_bounds__(256) void proj_kernel(
    const unsigned short* __restrict__ A, const unsigned short* __restrict__ Bw,
    float* __restrict__ C) {
  int blk = blockIdx.x;
  int bn = blk & 7;     // N/128 = 8
  int bm = blk >> 3;
  int tid = threadIdx.x, w = tid >> 6, l = tid & 63, lm = l & 15, lg = l >> 4;
  int m0 = bm * 128 + (w >> 1) * 64;
  int n0 = bn * 128 + (w & 1) * 64;

  f32x4 acc[4][4];
#pragma unroll
  for (int i = 0; i < 4; i++)
#pragma unroll
    for (int j = 0; j < 4; j++) acc[i][j] = (f32x4){0.f, 0.f, 0.f, 0.f};

  for (int k = 0; k < NE; k += 32) {
    s16x8 af[4], bf[4];
#pragma unroll
    for (int mb = 0; mb < 4; mb++)
      af[mb] = *(const s16x8*)(A + (size_t)(m0 + mb * 16 + lm) * NE + k + lg * 8);
#pragma unroll
    for (int nb = 0; nb < 4; nb++)
      bf[nb] = *(const s16x8*)(Bw + (size_t)(n0 + nb * 16 + lm) * NE + k + lg * 8);
#pragma unroll
    for (int mb = 0; mb < 4; mb++)
#pragma unroll
      for (int nb = 0; nb < 4; nb++)
        acc[mb][nb] = __builtin_amdgcn_mfma_f32_16x16x32_bf16(af[mb], bf[nb], acc[mb][nb], 0, 0, 0);
  }
#pragma unroll
  for (int mb = 0; mb < 4; mb++)
#pragma unroll
    for (int nb = 0; nb < 4; nb++)
#pragma unroll
      for (int r = 0; r < 4; r++)
        C[(size_t)(m0 + mb * 16 + lg * 4 + r) * NE + n0 + nb * 16 + lm] = acc[mb][nb][r];
}

extern "C" void kernel_launch(void* const* d_in, const int* in_sizes, int n_in,
                              void* d_out, int out_size, void* d_ws, size_t ws_size,
                              hipStream_t stream) {
  const float* x    = (const float*)d_in[0];
  const float* wqkv = (const float*)d_in[1];
  const float* wout = (const float*)d_in[2];
  float* out = (float*)d_out;
  char* ws = (char*)d_ws;

  size_t off = 0;
  unsigned short* xb  = (unsigned short*)(ws + off); off += (size_t)NBATCH * NS * NE * 2;
  unsigned short* wqb = (unsigned short*)(ws + off); off += (size_t)NH * 3 * ND * ND * 2;
  unsigned short* wob = (unsigned short*)(ws + off); off += (size_t)NE * NE * 2;
  unsigned short* Qb  = (unsigned short*)(ws + off); off += (size_t)NBATCH * NH * NS * ND * 2;
  unsigned short* Kb  = (unsigned short*)(ws + off); off += (size_t)NBATCH * NH * NS * ND * 2;
  unsigned short* Vt  = (unsigned short*)(ws + off); off += (size_t)NBATCH * NH * NS * ND * 2;
  unsigned short* AOb = (unsigned short*)(ws + off); off += (size_t)NBATCH * NS * NE * 2;

  cvt_kernel<<<2048, 256, 0, stream>>>(x, wqkv, wout, xb, wqb, wob);
  qkv_kernel<<<2048, 256, 0, stream>>>(xb, wqb, Qb, Kb, Vt);
  attn_kernel<<<1024, 256, 0, stream>>>(Qb, Kb, Vt, AOb);
  proj_kernel<<<512, 256, 0, stream>>>(AOb, wob, out);
}